// Round 1
// baseline (97.530 us; speedup 1.0000x reference)
//
#include <hip/hip_runtime.h>
#include <math.h>

#define NROWS 4096
#define DDIM  64
#define NBINS 4096
#define HIST_W    0.125f   // 4096 bins over [0, 512)
#define HIST_INVW 8.0f

// ws layout (4-byte units):
// [0     .. 4096 )  hist (u32)
// [4096  .. 8192 )  x_sq (f32)
// [8192  .. 12288)  y_sq (f32)
// [12288 .. 12304)  params: params[0] = c = -gamma * log2(e)

__global__ void prep_kernel(const float* __restrict__ X, const float* __restrict__ Y,
                            unsigned* __restrict__ hist, float* __restrict__ x_sq,
                            float* __restrict__ y_sq) {
    int gid = blockIdx.x * blockDim.x + threadIdx.x;   // 0..8191
    if (gid < NBINS) hist[gid] = 0u;
    const float* src = (gid < NROWS) ? (X + (size_t)gid * DDIM)
                                     : (Y + (size_t)(gid - NROWS) * DDIM);
    const float4* p = (const float4*)src;
    float s = 0.f;
#pragma unroll
    for (int i = 0; i < DDIM / 4; ++i) {
        float4 v = p[i];
        s = fmaf(v.x, v.x, s);
        s = fmaf(v.y, v.y, s);
        s = fmaf(v.z, v.z, s);
        s = fmaf(v.w, v.w, s);
    }
    if (gid < NROWS) x_sq[gid] = s;
    else             y_sq[gid - NROWS] = s;
}

// MODE 0: histogram pass (no output write).  MODE 1: exp-write pass.
template <int MODE>
__launch_bounds__(256, 2)
__global__ void pass_kernel(const float* __restrict__ X, const float* __restrict__ Y,
                            const float* __restrict__ x_sq, const float* __restrict__ y_sq,
                            unsigned* __restrict__ hist, const float* __restrict__ params,
                            float* __restrict__ out) {
    __shared__ float Xs[DDIM][128];
    __shared__ float Ys[DDIM][128];
    __shared__ unsigned lhist[MODE == 0 ? NBINS : 1];

    const int t  = threadIdx.x;
    const int i0 = blockIdx.y * 128;   // X rows
    const int j0 = blockIdx.x * 128;   // Y rows (output cols)

    if (MODE == 0) {
        for (int i = t; i < NBINS; i += 256) lhist[i] = 0u;
    }

    // Stage both tiles transposed: Xs[k][local_row]
#pragma unroll
    for (int s = 0; s < 8; ++s) {
        int f   = t + s * 256;        // 0..2047
        int row = f >> 4;             // 0..127
        int kq  = (f & 15) * 4;       // 0,4,...,60
        float4 vx = *(const float4*)(X + (size_t)(i0 + row) * DDIM + kq);
        Xs[kq + 0][row] = vx.x; Xs[kq + 1][row] = vx.y;
        Xs[kq + 2][row] = vx.z; Xs[kq + 3][row] = vx.w;
        float4 vy = *(const float4*)(Y + (size_t)(j0 + row) * DDIM + kq);
        Ys[kq + 0][row] = vy.x; Ys[kq + 1][row] = vy.y;
        Ys[kq + 2][row] = vy.z; Ys[kq + 3][row] = vy.w;
    }
    __syncthreads();

    const int tx = t & 15;   // 16 col-groups
    const int ty = t >> 4;   // 16 row-groups

    float acc[8][8];
#pragma unroll
    for (int r = 0; r < 8; ++r)
#pragma unroll
        for (int c = 0; c < 8; ++c) acc[r][c] = 0.f;

#pragma unroll 4
    for (int k = 0; k < DDIM; ++k) {
        float4 xa = *(const float4*)&Xs[k][8 * ty];
        float4 xb = *(const float4*)&Xs[k][8 * ty + 4];
        float4 ya = *(const float4*)&Ys[k][8 * tx];
        float4 yb = *(const float4*)&Ys[k][8 * tx + 4];
        float xr[8] = {xa.x, xa.y, xa.z, xa.w, xb.x, xb.y, xb.z, xb.w};
        float yc[8] = {ya.x, ya.y, ya.z, ya.w, yb.x, yb.y, yb.z, yb.w};
#pragma unroll
        for (int r = 0; r < 8; ++r)
#pragma unroll
            for (int c = 0; c < 8; ++c)
                acc[r][c] = fmaf(xr[r], yc[c], acc[r][c]);
    }

    float xs[8], ys[8];
#pragma unroll
    for (int r = 0; r < 8; ++r) xs[r] = x_sq[i0 + 8 * ty + r];
#pragma unroll
    for (int c = 0; c < 8; ++c) ys[c] = y_sq[j0 + 8 * tx + c];

    if (MODE == 0) {
#pragma unroll
        for (int r = 0; r < 8; ++r) {
#pragma unroll
            for (int c = 0; c < 8; ++c) {
                float dv = fmaf(-2.f, acc[r][c], xs[r] + ys[c]);
                int idx = (int)(dv * HIST_INVW);
                idx = idx < 0 ? 0 : (idx > NBINS - 1 ? NBINS - 1 : idx);
                atomicAdd(&lhist[idx], 1u);
            }
        }
        __syncthreads();
        for (int i = t; i < NBINS; i += 256) {
            unsigned cv = lhist[i];
            if (cv) atomicAdd(&hist[i], cv);
        }
    } else {
        const float cc = params[0];
#pragma unroll
        for (int r = 0; r < 8; ++r) {
            int row = i0 + 8 * ty + r;
            float o[8];
#pragma unroll
            for (int c = 0; c < 8; ++c) {
                float dv = fmaf(-2.f, acc[r][c], xs[r] + ys[c]);
                o[c] = __builtin_amdgcn_exp2f(cc * dv);
            }
            float4* po = (float4*)(out + (size_t)row * NROWS + j0 + 8 * tx);
            po[0] = make_float4(o[0], o[1], o[2], o[3]);
            po[1] = make_float4(o[4], o[5], o[6], o[7]);
        }
    }
}

__global__ void scan_kernel(const unsigned* __restrict__ hist, float* __restrict__ params) {
    __shared__ unsigned cnt[NBINS];
    __shared__ unsigned tsum[256];
    __shared__ float vmed[2];
    const int t = threadIdx.x;

    unsigned s = 0;
    for (int i = 0; i < NBINS / 256; ++i) {
        unsigned cv = hist[t * (NBINS / 256) + i];
        cnt[t * (NBINS / 256) + i] = cv;
        s += cv;
    }
    tsum[t] = s;
    __syncthreads();
    // inclusive prefix over the 256 thread-partials (Hillis-Steele)
    for (int off = 1; off < 256; off <<= 1) {
        unsigned v = (t >= off) ? tsum[t - off] : 0u;
        __syncthreads();
        tsum[t] += v;
        __syncthreads();
    }
    unsigned cum = (t == 0) ? 0u : tsum[t - 1];

    const unsigned K1 = 8388607u;  // L/2-1, L = 4096*4096
    const unsigned K2 = 8388608u;  // L/2
    for (int i = 0; i < NBINS / 256; ++i) {
        int b = t * (NBINS / 256) + i;
        unsigned cv = cnt[b];
        if (cv) {
            if (K1 >= cum && (K1 - cum) < cv) {
                float frac = ((float)(K1 - cum) + 0.5f) / (float)cv;
                vmed[0] = ((float)b + frac) * HIST_W;
            }
            if (K2 >= cum && (K2 - cum) < cv) {
                float frac = ((float)(K2 - cum) + 0.5f) / (float)cv;
                vmed[1] = ((float)b + frac) * HIST_W;
            }
        }
        cum += cv;
    }
    __syncthreads();
    if (t == 0) {
        double med   = 0.5 * ((double)vmed[0] + (double)vmed[1]);
        double gamma = 8.317766166719343 / med;               // ln(4096) / med
        params[0] = (float)(-gamma * 1.4426950408889634);     // -gamma * log2(e)
    }
}

extern "C" void kernel_launch(void* const* d_in, const int* in_sizes, int n_in,
                              void* d_out, int out_size, void* d_ws, size_t ws_size,
                              hipStream_t stream) {
    const float* X = (const float*)d_in[0];
    const float* Y = (const float*)d_in[1];
    float* out = (float*)d_out;

    unsigned* hist = (unsigned*)d_ws;
    float* x_sq    = (float*)d_ws + 4096;
    float* y_sq    = (float*)d_ws + 8192;
    float* params  = (float*)d_ws + 12288;

    prep_kernel<<<32, 256, 0, stream>>>(X, Y, hist, x_sq, y_sq);

    dim3 grid(NROWS / 128, NROWS / 128);  // 32 x 32
    pass_kernel<0><<<grid, 256, 0, stream>>>(X, Y, x_sq, y_sq, hist, params, out);
    scan_kernel<<<1, 256, 0, stream>>>(hist, params);
    pass_kernel<1><<<grid, 256, 0, stream>>>(X, Y, x_sq, y_sq, hist, params, out);
}

// Round 2
// 89.593 us; speedup vs baseline: 1.0886x; 1.0886x over previous
//
#include <hip/hip_runtime.h>
#include <math.h>

#define NROWS 4096
#define DDIM  64
#define NBINS 2048
#define HIST_W    0.25f    // 2048 bins over [0, 512)
#define HIST_INVW 4.0f
#define KCHUNK 32

// ws layout (4-byte units):
// [0     .. 2048 )  hist (u32)
// [2048  .. 6144 )  x_sq (f32)
// [6144  .. 10240)  y_sq (f32)
// [10240 .. 10256)  params: params[0] = c = -gamma * log2(e)

__global__ void prep_kernel(const float* __restrict__ X, const float* __restrict__ Y,
                            unsigned* __restrict__ hist, float* __restrict__ x_sq,
                            float* __restrict__ y_sq) {
    int gid = blockIdx.x * blockDim.x + threadIdx.x;   // 0..8191
    if (gid < NBINS) hist[gid] = 0u;
    const float* src = (gid < NROWS) ? (X + (size_t)gid * DDIM)
                                     : (Y + (size_t)(gid - NROWS) * DDIM);
    const float4* p = (const float4*)src;
    float s = 0.f;
#pragma unroll
    for (int i = 0; i < DDIM / 4; ++i) {
        float4 v = p[i];
        s = fmaf(v.x, v.x, s);
        s = fmaf(v.y, v.y, s);
        s = fmaf(v.z, v.z, s);
        s = fmaf(v.w, v.w, s);
    }
    if (gid < NROWS) x_sq[gid] = s;
    else             y_sq[gid - NROWS] = s;
}

// MODE 0: histogram pass (no output write).  MODE 1: exp-write pass.
template <int MODE>
__launch_bounds__(256, 4)
__global__ void pass_kernel(const float* __restrict__ X, const float* __restrict__ Y,
                            const float* __restrict__ x_sq, const float* __restrict__ y_sq,
                            unsigned* __restrict__ hist, const float* __restrict__ params,
                            float* __restrict__ out) {
    __shared__ float Xs[KCHUNK][128];   // [k][row], rows XOR-swizzled by ((k&7)<<2)
    __shared__ float Ys[KCHUNK][128];
    __shared__ unsigned lhist[MODE == 0 ? NBINS : 1];

    const int t  = threadIdx.x;
    const int i0 = blockIdx.y * 128;   // X rows
    const int j0 = blockIdx.x * 128;   // Y rows (output cols)

    if (MODE == 0) {
#pragma unroll
        for (int i = 0; i < NBINS / 256; ++i) lhist[t + i * 256] = 0u;
    }

    const int tx = t & 15;   // 16 col-groups
    const int ty = t >> 4;   // 16 row-groups

    // staging decomposition: thread owns a 4x4 block per matrix per chunk
    const int scb = t & 7;    // k-block within chunk (cols 4*scb..4*scb+3)
    const int srb = t >> 3;   // row-block (rows 4*srb..4*srb+3)

    float acc[8][8];
#pragma unroll
    for (int r = 0; r < 8; ++r)
#pragma unroll
        for (int c = 0; c < 8; ++c) acc[r][c] = 0.f;

    for (int ch = 0; ch < DDIM / KCHUNK; ++ch) {
        const int kc0 = ch * KCHUNK;
        if (ch) __syncthreads();   // protect LDS reuse

        // ---- stage X: load 4x4, transpose in regs, ds_write_b128 swizzled ----
        {
            const float* base = X + (size_t)(i0 + 4 * srb) * DDIM + kc0 + 4 * scb;
            float4 v0 = *(const float4*)(base + 0 * DDIM);
            float4 v1 = *(const float4*)(base + 1 * DDIM);
            float4 v2 = *(const float4*)(base + 2 * DDIM);
            float4 v3 = *(const float4*)(base + 3 * DDIM);
            float4 w[4];
            w[0] = make_float4(v0.x, v1.x, v2.x, v3.x);
            w[1] = make_float4(v0.y, v1.y, v2.y, v3.y);
            w[2] = make_float4(v0.z, v1.z, v2.z, v3.z);
            w[3] = make_float4(v0.w, v1.w, v2.w, v3.w);
#pragma unroll
            for (int j = 0; j < 4; ++j) {
                int k = 4 * scb + j;
                int swz = (k & 7) << 2;
                *(float4*)&Xs[k][(4 * srb) ^ swz] = w[j];
            }
        }
        // ---- stage Y ----
        {
            const float* base = Y + (size_t)(j0 + 4 * srb) * DDIM + kc0 + 4 * scb;
            float4 v0 = *(const float4*)(base + 0 * DDIM);
            float4 v1 = *(const float4*)(base + 1 * DDIM);
            float4 v2 = *(const float4*)(base + 2 * DDIM);
            float4 v3 = *(const float4*)(base + 3 * DDIM);
            float4 w[4];
            w[0] = make_float4(v0.x, v1.x, v2.x, v3.x);
            w[1] = make_float4(v0.y, v1.y, v2.y, v3.y);
            w[2] = make_float4(v0.z, v1.z, v2.z, v3.z);
            w[3] = make_float4(v0.w, v1.w, v2.w, v3.w);
#pragma unroll
            for (int j = 0; j < 4; ++j) {
                int k = 4 * scb + j;
                int swz = (k & 7) << 2;
                *(float4*)&Ys[k][(4 * srb) ^ swz] = w[j];
            }
        }
        __syncthreads();

#pragma unroll 8
        for (int k = 0; k < KCHUNK; ++k) {
            int swz = (k & 7) << 2;
            float4 xa = *(const float4*)&Xs[k][(8 * ty) ^ swz];
            float4 xb = *(const float4*)&Xs[k][(8 * ty + 4) ^ swz];
            float4 ya = *(const float4*)&Ys[k][(8 * tx) ^ swz];
            float4 yb = *(const float4*)&Ys[k][(8 * tx + 4) ^ swz];
            float xr[8] = {xa.x, xa.y, xa.z, xa.w, xb.x, xb.y, xb.z, xb.w};
            float yc[8] = {ya.x, ya.y, ya.z, ya.w, yb.x, yb.y, yb.z, yb.w};
#pragma unroll
            for (int r = 0; r < 8; ++r)
#pragma unroll
                for (int c = 0; c < 8; ++c)
                    acc[r][c] = fmaf(xr[r], yc[c], acc[r][c]);
        }
    }

    float xs[8], ys[8];
#pragma unroll
    for (int r = 0; r < 8; ++r) xs[r] = x_sq[i0 + 8 * ty + r];
#pragma unroll
    for (int c = 0; c < 8; ++c) ys[c] = y_sq[j0 + 8 * tx + c];

    if (MODE == 0) {
#pragma unroll
        for (int r = 0; r < 8; ++r) {
#pragma unroll
            for (int c = 0; c < 8; ++c) {
                float dv = fmaf(-2.f, acc[r][c], xs[r] + ys[c]);
                int idx = (int)(dv * HIST_INVW);
                idx = idx < 0 ? 0 : (idx > NBINS - 1 ? NBINS - 1 : idx);
                atomicAdd(&lhist[idx], 1u);
            }
        }
        __syncthreads();
#pragma unroll
        for (int i = 0; i < NBINS / 256; ++i) {
            unsigned cv = lhist[t + i * 256];
            if (cv) atomicAdd(&hist[t + i * 256], cv);
        }
    } else {
        const float cc = params[0];
#pragma unroll
        for (int r = 0; r < 8; ++r) {
            int row = i0 + 8 * ty + r;
            float o[8];
#pragma unroll
            for (int c = 0; c < 8; ++c) {
                float dv = fmaf(-2.f, acc[r][c], xs[r] + ys[c]);
                o[c] = __builtin_amdgcn_exp2f(cc * dv);
            }
            float4* po = (float4*)(out + (size_t)row * NROWS + j0 + 8 * tx);
            po[0] = make_float4(o[0], o[1], o[2], o[3]);
            po[1] = make_float4(o[4], o[5], o[6], o[7]);
        }
    }
}

__global__ void scan_kernel(const unsigned* __restrict__ hist, float* __restrict__ params) {
    __shared__ unsigned cnt[NBINS];
    __shared__ unsigned tsum[256];
    __shared__ float vmed[2];
    const int t = threadIdx.x;

    unsigned s = 0;
    for (int i = 0; i < NBINS / 256; ++i) {
        unsigned cv = hist[t * (NBINS / 256) + i];
        cnt[t * (NBINS / 256) + i] = cv;
        s += cv;
    }
    tsum[t] = s;
    __syncthreads();
    // inclusive prefix over the 256 thread-partials (Hillis-Steele)
    for (int off = 1; off < 256; off <<= 1) {
        unsigned v = (t >= off) ? tsum[t - off] : 0u;
        __syncthreads();
        tsum[t] += v;
        __syncthreads();
    }
    unsigned cum = (t == 0) ? 0u : tsum[t - 1];

    const unsigned K1 = 8388607u;  // L/2-1, L = 4096*4096
    const unsigned K2 = 8388608u;  // L/2
    for (int i = 0; i < NBINS / 256; ++i) {
        int b = t * (NBINS / 256) + i;
        unsigned cv = cnt[b];
        if (cv) {
            if (K1 >= cum && (K1 - cum) < cv) {
                float frac = ((float)(K1 - cum) + 0.5f) / (float)cv;
                vmed[0] = ((float)b + frac) * HIST_W;
            }
            if (K2 >= cum && (K2 - cum) < cv) {
                float frac = ((float)(K2 - cum) + 0.5f) / (float)cv;
                vmed[1] = ((float)b + frac) * HIST_W;
            }
        }
        cum += cv;
    }
    __syncthreads();
    if (t == 0) {
        double med   = 0.5 * ((double)vmed[0] + (double)vmed[1]);
        double gamma = 8.317766166719343 / med;               // ln(4096) / med
        params[0] = (float)(-gamma * 1.4426950408889634);     // -gamma * log2(e)
    }
}

extern "C" void kernel_launch(void* const* d_in, const int* in_sizes, int n_in,
                              void* d_out, int out_size, void* d_ws, size_t ws_size,
                              hipStream_t stream) {
    const float* X = (const float*)d_in[0];
    const float* Y = (const float*)d_in[1];
    float* out = (float*)d_out;

    unsigned* hist = (unsigned*)d_ws;
    float* x_sq    = (float*)d_ws + 2048;
    float* y_sq    = (float*)d_ws + 6144;
    float* params  = (float*)d_ws + 10240;

    prep_kernel<<<32, 256, 0, stream>>>(X, Y, hist, x_sq, y_sq);

    dim3 grid(NROWS / 128, NROWS / 128);  // 32 x 32
    pass_kernel<0><<<grid, 256, 0, stream>>>(X, Y, x_sq, y_sq, hist, params, out);
    scan_kernel<<<1, 256, 0, stream>>>(hist, params);
    pass_kernel<1><<<grid, 256, 0, stream>>>(X, Y, x_sq, y_sq, hist, params, out);
}

// Round 3
// 61.981 us; speedup vs baseline: 1.5736x; 1.4455x over previous
//
#include <hip/hip_runtime.h>
#include <math.h>

#define NROWS 4096
#define DDIM  64
#define NBINS 2048
#define HIST_W    0.25f    // 2048 bins over [0, 512)
#define HIST_INVW 4.0f

// ws layout (bytes):
// [0      .. 8192  )  hist (2048 u32)
// [8192   .. 24576 )  x_sq (4096 f32)
// [24576  .. 40960 )  y_sq (4096 f32)
// [40960  .. 40976 )  params: params[0] = c = -gamma*log2(e)
// [65536  .. +512K )  Xh   (4096x64 bf16)
// ...                 Xl, Yh, Yl   — total ws needed = 2,162,688 B (~2.07 MB)

typedef __attribute__((ext_vector_type(8))) short short8;
typedef __attribute__((ext_vector_type(4))) float f32x4;

__device__ inline unsigned short f2bf(float f) {           // RNE f32 -> bf16 bits
    unsigned u = __builtin_bit_cast(unsigned, f);
    u += 0x7FFFu + ((u >> 16) & 1u);
    return (unsigned short)(u >> 16);
}
__device__ inline float bf2f(unsigned short h) {
    unsigned u = ((unsigned)h) << 16;
    return __builtin_bit_cast(float, u);
}

__global__ void prep_kernel(const float* __restrict__ X, const float* __restrict__ Y,
                            unsigned short* __restrict__ Xh, unsigned short* __restrict__ Xl,
                            unsigned short* __restrict__ Yh, unsigned short* __restrict__ Yl,
                            float* __restrict__ x_sq, float* __restrict__ y_sq,
                            unsigned* __restrict__ hist) {
    int gid = blockIdx.x * blockDim.x + threadIdx.x;       // 0..65535
    if (gid < NBINS) hist[gid] = 0u;
    int row = gid >> 3, kb = gid & 7;                      // 8 elems per thread
    int r = (row < NROWS) ? row : row - NROWS;
    const float* src = ((row < NROWS) ? X : Y) + (size_t)r * DDIM + kb * 8;
    unsigned short* dh = (row < NROWS) ? Xh : Yh;
    unsigned short* dl = (row < NROWS) ? Xl : Yl;
    float* sq = (row < NROWS) ? x_sq : y_sq;

    float4 a = *(const float4*)src;
    float4 b = *(const float4*)(src + 4);
    float v[8] = {a.x, a.y, a.z, a.w, b.x, b.y, b.z, b.w};
    short8 vh, vl;
    float s = 0.f;
#pragma unroll
    for (int j = 0; j < 8; ++j) {
        s = fmaf(v[j], v[j], s);
        unsigned short h = f2bf(v[j]);
        vh[j] = (short)h;
        vl[j] = (short)f2bf(v[j] - bf2f(h));
    }
    // 8 consecutive lanes share a row -> reduce
    s += __shfl_xor(s, 1);
    s += __shfl_xor(s, 2);
    s += __shfl_xor(s, 4);
    if (kb == 0) sq[r] = s;
    size_t o = (size_t)r * DDIM + kb * 8;
    *(short8*)(dh + o) = vh;
    *(short8*)(dl + o) = vl;
}

// MODE 0: sampled histogram pass (grid 4x32 -> cols j0 = bx*1024).
// MODE 1: full exp-write pass  (grid 32x32).
template <int MODE>
__launch_bounds__(256, 4)
__global__ void pass_kernel(const unsigned short* __restrict__ Xh, const unsigned short* __restrict__ Xl,
                            const unsigned short* __restrict__ Yh, const unsigned short* __restrict__ Yl,
                            const float* __restrict__ x_sq, const float* __restrict__ y_sq,
                            unsigned* __restrict__ hist, const float* __restrict__ params,
                            float* __restrict__ out) {
    __shared__ unsigned lhist[MODE == 0 ? NBINS : 1];
    const int t    = threadIdx.x;
    const int wave = t >> 6;
    const int lane = t & 63;
    const int i0 = blockIdx.y * 128 + (wave >> 1) * 64;                       // X rows
    const int j0 = blockIdx.x * (MODE == 0 ? 1024 : 128) + (wave & 1) * 64;   // Y rows

    if (MODE == 0) {
        for (int i = t; i < NBINS; i += 256) lhist[i] = 0u;
        __syncthreads();
    }

    const int fr = lane & 15;          // fragment row/col
    const int fk = (lane >> 4) * 8;    // fragment k base

    f32x4 acc[4][4];
#pragma unroll
    for (int r = 0; r < 4; ++r)
#pragma unroll
        for (int c = 0; c < 4; ++c) acc[r][c] = (f32x4){0.f, 0.f, 0.f, 0.f};

    auto step = [&](const unsigned short* A, const unsigned short* B, int kh) {
        short8 af[4], bg[4];
#pragma unroll
        for (int g = 0; g < 4; ++g) {
            af[g] = *(const short8*)(A + (size_t)(i0 + g * 16 + fr) * DDIM + kh * 32 + fk);
            bg[g] = *(const short8*)(B + (size_t)(j0 + g * 16 + fr) * DDIM + kh * 32 + fk);
        }
#pragma unroll
        for (int r = 0; r < 4; ++r)
#pragma unroll
            for (int c = 0; c < 4; ++c)
                acc[r][c] = __builtin_amdgcn_mfma_f32_16x16x32_bf16(af[r], bg[c], acc[r][c], 0, 0, 0);
    };

    // X*Y' ~= Xh*Yh' + Xl*Yh' + Xh*Yl'   (each over K=64 as two K=32 halves)
    step(Xh, Yh, 0); step(Xh, Yh, 1);
    step(Xl, Yh, 0); step(Xl, Yh, 1);
    step(Xh, Yl, 0); step(Xh, Yl, 1);

    float ysv[4];
#pragma unroll
    for (int c = 0; c < 4; ++c) ysv[c] = y_sq[j0 + c * 16 + fr];
    const int rb = (lane >> 4) * 4;

    if (MODE == 0) {
#pragma unroll
        for (int r = 0; r < 4; ++r) {
#pragma unroll
            for (int q = 0; q < 4; ++q) {
                int row = i0 + r * 16 + rb + q;
                float xs = x_sq[row];
#pragma unroll
                for (int c = 0; c < 4; ++c) {
                    float dv = fmaf(-2.f, acc[r][c][q], xs + ysv[c]);
                    int idx = (int)(dv * HIST_INVW);
                    idx = idx < 0 ? 0 : (idx > NBINS - 1 ? NBINS - 1 : idx);
                    atomicAdd(&lhist[idx], 1u);
                }
            }
        }
        __syncthreads();
        for (int i = t; i < NBINS; i += 256) {
            unsigned cv = lhist[i];
            if (cv) atomicAdd(&hist[i], cv);
        }
    } else {
        const float cc = params[0];
#pragma unroll
        for (int r = 0; r < 4; ++r) {
#pragma unroll
            for (int q = 0; q < 4; ++q) {
                int row = i0 + r * 16 + rb + q;
                float xs = x_sq[row];
                float o[4];
#pragma unroll
                for (int c = 0; c < 4; ++c) {
                    float dv = fmaf(-2.f, acc[r][c][q], xs + ysv[c]);
                    o[c] = __builtin_amdgcn_exp2f(cc * dv);
                }
                float* po = out + (size_t)row * NROWS + j0 + fr;
#pragma unroll
                for (int c = 0; c < 4; ++c) po[c * 16] = o[c];
            }
        }
    }
}

__global__ void scan_kernel(const unsigned* __restrict__ hist, float* __restrict__ params) {
    __shared__ unsigned cnt[NBINS];
    __shared__ unsigned tsum[256];
    __shared__ float vmed[2];
    const int t = threadIdx.x;

    unsigned s = 0;
    for (int i = 0; i < NBINS / 256; ++i) {
        unsigned cv = hist[t * (NBINS / 256) + i];
        cnt[t * (NBINS / 256) + i] = cv;
        s += cv;
    }
    tsum[t] = s;
    __syncthreads();
    for (int off = 1; off < 256; off <<= 1) {
        unsigned v = (t >= off) ? tsum[t - off] : 0u;
        __syncthreads();
        tsum[t] += v;
        __syncthreads();
    }
    unsigned cum = (t == 0) ? 0u : tsum[t - 1];

    // sampled count: 128 blocks * 16384 = 2,097,152
    const unsigned K1 = 1048575u;
    const unsigned K2 = 1048576u;
    for (int i = 0; i < NBINS / 256; ++i) {
        int b = t * (NBINS / 256) + i;
        unsigned cv = cnt[b];
        if (cv) {
            if (K1 >= cum && (K1 - cum) < cv) {
                float frac = ((float)(K1 - cum) + 0.5f) / (float)cv;
                vmed[0] = ((float)b + frac) * HIST_W;
            }
            if (K2 >= cum && (K2 - cum) < cv) {
                float frac = ((float)(K2 - cum) + 0.5f) / (float)cv;
                vmed[1] = ((float)b + frac) * HIST_W;
            }
        }
        cum += cv;
    }
    __syncthreads();
    if (t == 0) {
        double med   = 0.5 * ((double)vmed[0] + (double)vmed[1]);
        double gamma = 8.317766166719343 / med;               // ln(4096) / med
        params[0] = (float)(-gamma * 1.4426950408889634);     // -gamma * log2(e)
    }
}

extern "C" void kernel_launch(void* const* d_in, const int* in_sizes, int n_in,
                              void* d_out, int out_size, void* d_ws, size_t ws_size,
                              hipStream_t stream) {
    const float* X = (const float*)d_in[0];
    const float* Y = (const float*)d_in[1];
    float* out = (float*)d_out;

    unsigned* hist = (unsigned*)d_ws;
    float* x_sq    = (float*)((char*)d_ws + 8192);
    float* y_sq    = (float*)((char*)d_ws + 24576);
    float* params  = (float*)((char*)d_ws + 40960);
    unsigned short* Xh = (unsigned short*)((char*)d_ws + 65536);
    unsigned short* Xl = Xh + (size_t)NROWS * DDIM;
    unsigned short* Yh = Xl + (size_t)NROWS * DDIM;
    unsigned short* Yl = Yh + (size_t)NROWS * DDIM;

    prep_kernel<<<256, 256, 0, stream>>>(X, Y, Xh, Xl, Yh, Yl, x_sq, y_sq, hist);
    pass_kernel<0><<<dim3(4, 32), 256, 0, stream>>>(Xh, Xl, Yh, Yl, x_sq, y_sq, hist, params, out);
    scan_kernel<<<1, 256, 0, stream>>>(hist, params);
    pass_kernel<1><<<dim3(32, 32), 256, 0, stream>>>(Xh, Xl, Yh, Yl, x_sq, y_sq, hist, params, out);
}